// Round 1
// baseline (145.232 us; speedup 1.0000x reference)
//
#include <hip/hip_runtime.h>

#define A_DIM 200
#define F_DIM 53
#define NAF 38
#define NPHYS 15
#define R_OUT 20
#define C_OUT 1024
#define BLOCK 256

__global__ __launch_bounds__(BLOCK, 3) void pggcn_kernel(
    const float* __restrict__ inputs,  // (B, 200, 53)
    const int*   __restrict__ i_s,     // (B,)
    const float* __restrict__ W_self,  // (38,20)
    const float* __restrict__ W_nei,   // (38,20)
    const float* __restrict__ b_r,     // (20,)
    const float* __restrict__ Wc,      // (20,1024)
    const float* __restrict__ bc,      // (1024,)
    const float* __restrict__ W1,      // (1024,32)
    const float* __restrict__ b1,      // (32,)
    const float* __restrict__ W5,      // (32,16)
    const float* __restrict__ b5,      // (16,)
    const float* __restrict__ W6,      // (16,1)
    const float* __restrict__ b6,      // (1,)
    const float* __restrict__ W7,      // (16,1)
    const float* __restrict__ b7,      // (1,)
    float* __restrict__ out)           // (B,16)
{
    __shared__ __align__(16) float s_atom[A_DIM * NAF];   // 30400 B (aliased later)
    __shared__ __align__(16) float s_h[A_DIM * R_OUT];    // 16000 B
    __shared__ float s_wself[NAF * R_OUT];                // 3040 B
    __shared__ float s_aggp[6 * NAF];                     // 912 B
    __shared__ float s_agg[NAF];
    __shared__ float s_hnei[R_OUT];
    __shared__ float s_phys[NPHYS];

    // aliases into s_atom (dead after phase D)
    float* s_pool = s_atom;                 // 1024
    float* s_red  = s_atom + C_OUT;         // 256
    float* s_d1   = s_atom + C_OUT + 256;   // 32
    float* s_d5   = s_atom + C_OUT + 288;   // 16

    const int b = blockIdx.x;
    const int t = threadIdx.x;
    const int ns = i_s[b];                       // 1..199
    const float* in_b = inputs + (size_t)b * (A_DIM * F_DIM);

    // ---- stage W_self, physics, active atom rows ----
    for (int i = t; i < NAF * R_OUT; i += BLOCK) s_wself[i] = W_self[i];
    if (t < NPHYS) s_phys[t] = in_b[NAF + t];
    const int tot = ns * NAF;
    for (int i = t; i < tot; i += BLOCK) {
        int r = i / NAF;
        int f = i - r * NAF;
        s_atom[i] = in_b[r * F_DIM + f];
    }
    __syncthreads();

    // ---- agg[f] = sum_{r<ns} atom[r][f] (6 partial groups) ----
    if (t < 6 * NAF) {
        int f = t % NAF, g = t / NAF;
        float s = 0.f;
        for (int r = g; r < ns; r += 6) s += s_atom[r * NAF + f];
        s_aggp[t] = s;
    }
    __syncthreads();
    if (t < NAF) {
        float s = 0.f;
        #pragma unroll
        for (int g = 0; g < 6; ++g) s += s_aggp[g * NAF + t];
        s_agg[t] = s;
    }
    __syncthreads();

    // ---- hnei[j] = agg @ W_nei + b_r ----
    if (t < R_OUT) {
        float s = b_r[t];
        #pragma unroll
        for (int f = 0; f < NAF; ++f) s += s_agg[f] * W_nei[f * R_OUT + t];
        s_hnei[t] = s;
    }
    __syncthreads();

    // ---- h rows: h[r][j] = relu(atom_row @ W_self[:,j] + hnei[j]) ----
    {
        int j = t % R_OUT;
        int rg = t / R_OUT;                  // 0..12 (240 active threads)
        if (rg < 12) {
            float wcol[NAF];
            #pragma unroll
            for (int f = 0; f < NAF; ++f) wcol[f] = s_wself[f * R_OUT + j];
            float hn = s_hnei[j];
            for (int r = rg; r < ns; r += 12) {
                const float* arow = &s_atom[r * NAF];
                float acc = hn;
                #pragma unroll
                for (int f = 0; f < NAF; ++f) acc += arow[f] * wcol[f];
                s_h[r * R_OUT + j] = fmaxf(acc, 0.f);
            }
        }
    }
    __syncthreads();

    // ---- main: pooled[j] = sum_r relu(h_row @ Wc[:,j] + bc[j]); cols 4t..4t+3 ----
    {
        float4 wc[R_OUT];
        #pragma unroll
        for (int k = 0; k < R_OUT; ++k)
            wc[k] = *reinterpret_cast<const float4*>(&Wc[k * C_OUT + 4 * t]);
        const float4 bcv = *reinterpret_cast<const float4*>(&bc[4 * t]);
        float4 pool = make_float4(0.f, 0.f, 0.f, 0.f);
        for (int r = 0; r < ns; ++r) {
            const float4 h0 = *reinterpret_cast<const float4*>(&s_h[r * R_OUT + 0]);
            const float4 h1 = *reinterpret_cast<const float4*>(&s_h[r * R_OUT + 4]);
            const float4 h2 = *reinterpret_cast<const float4*>(&s_h[r * R_OUT + 8]);
            const float4 h3 = *reinterpret_cast<const float4*>(&s_h[r * R_OUT + 12]);
            const float4 h4 = *reinterpret_cast<const float4*>(&s_h[r * R_OUT + 16]);
            float4 acc = bcv;
            const float hv[R_OUT] = {h0.x,h0.y,h0.z,h0.w, h1.x,h1.y,h1.z,h1.w,
                                     h2.x,h2.y,h2.z,h2.w, h3.x,h3.y,h3.z,h3.w,
                                     h4.x,h4.y,h4.z,h4.w};
            #pragma unroll
            for (int k = 0; k < R_OUT; ++k) {
                acc.x += hv[k] * wc[k].x;
                acc.y += hv[k] * wc[k].y;
                acc.z += hv[k] * wc[k].z;
                acc.w += hv[k] * wc[k].w;
            }
            pool.x += fmaxf(acc.x, 0.f);
            pool.y += fmaxf(acc.y, 0.f);
            pool.z += fmaxf(acc.z, 0.f);
            pool.w += fmaxf(acc.w, 0.f);
        }
        __syncthreads();   // s_atom fully dead; safe to overwrite alias region
        *reinterpret_cast<float4*>(&s_pool[4 * t]) = pool;
    }
    __syncthreads();

    // ---- d1 = relu(pooled @ W1 + b1): m = t%32, 8 partial parts ----
    {
        int m = t & 31, part = t >> 5;
        float s = 0.f;
        int j0 = part * 128;
        for (int j = j0; j < j0 + 128; ++j) s += s_pool[j] * W1[j * 32 + m];
        s_red[part * 32 + m] = s;
    }
    __syncthreads();
    if (t < 32) {
        float s = b1[t];
        #pragma unroll
        for (int p = 0; p < 8; ++p) s += s_red[p * 32 + t];
        s_d1[t] = fmaxf(s, 0.f);
    }
    __syncthreads();

    // ---- d5 = relu(d1 @ W5 + b5) ----
    if (t < 16) {
        float s = b5[t];
        #pragma unroll
        for (int m = 0; m < 32; ++m) s += s_d1[m] * W5[m * 16 + t];
        s_d5[t] = fmaxf(s, 0.f);
    }
    __syncthreads();

    // ---- model_var, final merge ----
    if (t == 0) {
        float mv = b6[0];
        #pragma unroll
        for (int m = 0; m < 16; ++m) mv += s_d5[m] * W6[m];
        float o = b7[0] + W7[0] * mv;
        #pragma unroll
        for (int i = 0; i < NPHYS; ++i) o += W7[i + 1] * s_phys[i];
        out[(size_t)b * 16] = o;
    }
    if (t < NPHYS) out[(size_t)b * 16 + 1 + t] = s_phys[t];
}

extern "C" void kernel_launch(void* const* d_in, const int* in_sizes, int n_in,
                              void* d_out, int out_size, void* d_ws, size_t ws_size,
                              hipStream_t stream) {
    const float* inputs = (const float*)d_in[0];
    const int*   i_s    = (const int*)d_in[1];
    const float* W_self = (const float*)d_in[2];
    const float* W_nei  = (const float*)d_in[3];
    const float* b_r    = (const float*)d_in[4];
    const float* Wc     = (const float*)d_in[5];
    const float* bc     = (const float*)d_in[6];
    const float* W1     = (const float*)d_in[7];
    const float* b1     = (const float*)d_in[8];
    const float* W5     = (const float*)d_in[9];
    const float* b5     = (const float*)d_in[10];
    const float* W6     = (const float*)d_in[11];
    const float* b6     = (const float*)d_in[12];
    const float* W7     = (const float*)d_in[13];
    const float* b7     = (const float*)d_in[14];
    float* out = (float*)d_out;

    const int B = in_sizes[1];   // 1024
    pggcn_kernel<<<B, BLOCK, 0, stream>>>(inputs, i_s, W_self, W_nei, b_r, Wc, bc,
                                          W1, b1, W5, b5, W6, b6, W7, b7, out);
}